// Round 10
// baseline (217.045 us; speedup 1.0000x reference)
//
#include <hip/hip_runtime.h>
#include <stdint.h>

// Graphormer layer constants
#define NB 128   // batch
#define NN 256   // nodes
#define NE 1024  // edges
#define ND 128   // model dim
#define NH 8     // heads
#define NDK 16   // head dim
#define NEGV -9.0e15f

typedef unsigned short u16;
typedef unsigned int u32;
typedef unsigned char u8;
typedef __attribute__((ext_vector_type(8))) short short8;
typedef __attribute__((ext_vector_type(4))) float float4v;
typedef __attribute__((ext_vector_type(2))) float f32x2;

__device__ __forceinline__ float bf2f(u16 u) { return __uint_as_float(((u32)u) << 16); }
__device__ __forceinline__ u16 f2bf(float f) {
    u32 u = __float_as_uint(f);
    u += 0x7fffu + ((u >> 16) & 1u);  // round-to-nearest-even
    return (u16)(u >> 16);
}
__device__ __forceinline__ float ldf(const void* p, size_t i, int f32) {
    return f32 ? ((const float*)p)[i] : bf2f(((const u16*)p)[i]);
}
__device__ __forceinline__ void stf(void* p, size_t i, int f32, float v) {
    if (f32) ((float*)p)[i] = v;
    else ((u16*)p)[i] = f2bf(v);
}
__device__ __forceinline__ void unpack8(uint4 a, float* o) {
    o[0] = bf2f(a.x & 0xffff); o[1] = bf2f(a.x >> 16);
    o[2] = bf2f(a.y & 0xffff); o[3] = bf2f(a.y >> 16);
    o[4] = bf2f(a.z & 0xffff); o[5] = bf2f(a.z >> 16);
    o[6] = bf2f(a.w & 0xffff); o[7] = bf2f(a.w >> 16);
}
// {low bf16, high bf16} of a u32 word -> f32x2
__device__ __forceinline__ f32x2 bfpair(u32 w) {
    return (f32x2){__uint_as_float(w << 16), __uint_as_float(w & 0xffff0000u)};
}
// pack two f32 -> two bf16 (round-nearest-up; p>=0 finite). Compiler-visible
// ops only: safe consumer of TRANS (v_exp) results. (Inline-asm cvt_pk here
// hit the TRANS->inline-asm hazard -> NaN, r2-r5 post-mortem.)
__device__ __forceinline__ u32 pk_bf(float a, float b) {
    return ((__float_as_uint(a) + 0x8000u) >> 16) |
           ((__float_as_uint(b) + 0x8000u) & 0xffff0000u);
}
union Pack8 { u16 u[8]; u32 w[4]; short8 v; };

// ---------------------------------------------------------------------------
// Per-wave format self-detect (replaces the k_detect kernel + flags buffer).
// Every wave reads the SAME first 1KB of x / mask -> deterministic, identical
// result in all waves/blocks. f32 probe covers 256 low-halfwords (false-neg
// P = 0.76^256 ~ 1e-31); mask probe covers 1024 bytes. (r8/r9-verified PASS)
// ---------------------------------------------------------------------------
__device__ __forceinline__ int wave_detect_f32(const u16* x16) {
    int lane = threadIdx.x & 63;
    uint4 a = *(const uint4*)(x16 + lane * 8);
    u32 w[4] = {a.x, a.y, a.z, a.w};
    u32 ev = 0;
#pragma unroll
    for (int j = 0; j < 4; ++j) {
        ev |= ((((w[j] & 0xffffu) >> 7) & 0xffu) >= 0xC2u) ? 1u : 0u;
        ev |= (((w[j] >> 23) & 0xffu) >= 0xC2u) ? 1u : 0u;
    }
#pragma unroll
    for (int off = 32; off; off >>= 1) ev |= (u32)__shfl_xor((int)ev, off, 64);
    return ev ? 1 : 0;
}
__device__ __forceinline__ int wave_detect_mw(const u8* m8) {
    int lane = threadIdx.x & 63;
    uint4 m = *(const uint4*)(m8 + lane * 16);
    u32 w[4] = {m.x, m.y, m.z, m.w};
    u32 g1 = 0, mx = 0;
#pragma unroll
    for (int j = 0; j < 4; ++j) {
        u32 b0 = w[j] & 0xffu, b1 = (w[j] >> 8) & 0xffu;
        u32 b2 = (w[j] >> 16) & 0xffu, b3 = w[j] >> 24;
        g1 |= b1;  // (idx&3)==1 bytes
        u32 ma = b0 > b1 ? b0 : b1, mb2 = b2 > b3 ? b2 : b3;
        u32 mc = ma > mb2 ? ma : mb2;
        mx = mx > mc ? mx : mc;
    }
#pragma unroll
    for (int off = 32; off; off >>= 1) {
        g1 |= (u32)__shfl_xor((int)g1, off, 64);
        u32 o = (u32)__shfl_xor((int)mx, off, 64);
        mx = mx > o ? mx : o;
    }
    return (g1 == 0) ? 4 : ((mx <= 1u) ? 1 : 2);
}

// ---------------------------------------------------------------------------
// Fused preprocessing (r9-verified): blocks 0..248 do wmean (129) + packB
// (120) on 64 active lanes; blocks 249..376 do per-batch CSR writing the
// sort permutation posG[e]=pos (decoupled from edge features).
// ---------------------------------------------------------------------------
__global__ __launch_bounds__(256) void k_pre(const u16* x16,
                                             const void* Wew, const void* Web,
                                             float* wmean,
                                             const void* Wq, const void* Wk,
                                             const void* Wv, u16* WP,
                                             const int* ei, float* degr, float* degc,
                                             int* rowstartG, u16* colsG, u16* posG) {
    int bid = blockIdx.x, tid = threadIdx.x;
    if (bid < 249) {
        if (tid < 64) {
            int f32 = wave_detect_f32(x16);
            int lane = tid;
            if (bid < 129) {
                int k = bid;
                const void* src = (k < 128) ? Wew : Web;
                size_t base = (k < 128) ? (size_t)k * ND : 0;
                float s = ldf(src, base + lane, f32) + ldf(src, base + lane + 64, f32);
#pragma unroll
                for (int off = 32; off; off >>= 1) s += __shfl_xor(s, off, 64);
                if (lane == 0) wmean[k] = s * (1.0f / ND);
            } else {
                int id = bid - 129;
                int kT = id / 24, nT = id % 24;
                int col = lane & 15, quad = lane >> 4;
                int n = nT * 16 + col;
                int mat = n >> 7, nm = n & 127;
                const void* W = (mat == 0) ? Wq : (mat == 1) ? Wk : Wv;
                Pack8 c;
#pragma unroll
                for (int j = 0; j < 8; ++j) {
                    int k = kT * 32 + quad * 8 + j;
                    c.u[j] = (k < 130) ? f2bf(ldf(W, (size_t)k * ND + nm, f32)) : (u16)0;
                }
                *(short8*)(WP + ((size_t)(kT * 24 + nT) * 64 + lane) * 8) = c.v;
            }
        }
        return;
    }
    // ---- CSR for batch b (verbatim r6 body; feats scatter -> posG perm) ----
    __shared__ int cr[NN], cc[NN], offs[NN], rs[NN + 1];
    int b = bid - 249;
    cr[tid] = 0; cc[tid] = 0;
    __syncthreads();
    const int* rows = ei + (size_t)b * 2 * NE;   // (B,2,E)
    const int* cols = rows + NE;
    for (int e = tid; e < NE; e += 256) {
        atomicAdd(&cr[rows[e]], 1);
        atomicAdd(&cc[cols[e]], 1);
    }
    __syncthreads();
    degr[b * NN + tid] = (float)cr[tid];
    degc[b * NN + tid] = (float)cc[tid];
    if (tid == 0) {
        int a = 0;
        for (int n = 0; n < NN; ++n) { rs[n] = a; a += cr[n]; }
        rs[NN] = a;
    }
    __syncthreads();
    offs[tid] = rs[tid];
    rowstartG[b * (NN + 1) + tid] = rs[tid];
    if (tid == 0) rowstartG[b * (NN + 1) + NN] = rs[NN];
    __syncthreads();
    for (int e = tid; e < NE; e += 256) {
        int r = rows[e];
        int pos = atomicAdd(&offs[r], 1);
        colsG[(size_t)b * NE + pos] = (u16)cols[e];
        posG[(size_t)b * NE + e] = (u16)pos;
    }
}

// ---------------------------------------------------------------------------
// Fused middle stage (r10): k_gemm and k_efeat are mutually independent
// (both consumed only by k_attn) -> one launch, block-range split.
// Blocks 0..511: MFMA QKV GEMM (verbatim r9 body).
// Blocks 512..8703: edge features, saturating 16-lanes/edge form (verbatim
// r9 body), scattered directly to sorted slot via posG.
// Overlaps efeat's BW-bound phase with gemm's MFMA phase; -1 launch gap.
// ---------------------------------------------------------------------------
__global__ __launch_bounds__(256) void k_mid(const u16* x16, const void* x,
                                             const float* degr, const float* degc,
                                             const u16* WP, u16* qw, u16* kw,
                                             u16* vw, u16* vt,
                                             const void* ea, const float* wmean,
                                             const u16* posG, float* featsG) {
    __shared__ __align__(16) float swm[132];
    int bid = blockIdx.x, tid = threadIdx.x;
    if (bid < 512) {
        // ---- GEMM body ----
        int w = tid >> 6, lane = tid & 63;
        int quad = lane >> 4, col = lane & 15;
        int m0 = bid * 64 + w * 16;
        int row = m0 + col;
        int f32 = wave_detect_f32(x16);

        float4v acc[24];
#pragma unroll
        for (int t = 0; t < 24; ++t) acc[t] = (float4v){0.f, 0.f, 0.f, 0.f};

        const short8* wp = (const short8*)WP;
        for (int kT = 0; kT < 5; ++kT) {
            short8 a;
            if (kT < 4) {
                if (!f32) {
                    a = *(const short8*)((const u16*)x + (size_t)row * ND + kT * 32 + quad * 8);
                } else {
                    const float* xf = (const float*)x + (size_t)row * ND + kT * 32 + quad * 8;
                    Pack8 c;
#pragma unroll
                    for (int j = 0; j < 8; ++j) c.u[j] = f2bf(xf[j]);
                    a = c.v;
                }
            } else {
                Pack8 c;
#pragma unroll
                for (int j = 0; j < 8; ++j) c.u[j] = 0;
                if (quad == 0) {
                    c.u[0] = f2bf(degr[row]);
                    c.u[1] = f2bf(degc[row]);
                }
                a = c.v;
            }
#pragma unroll
            for (int nT = 0; nT < 24; ++nT) {
                short8 bfr = wp[(size_t)(kT * 24 + nT) * 64 + lane];
                acc[nT] = __builtin_amdgcn_mfma_f32_16x16x32_bf16(a, bfr, acc[nT], 0, 0, 0);
            }
        }
        int bb = m0 >> 8;
        int nodebase = (m0 & 255) + quad * 4;
#pragma unroll
        for (int nT = 0; nT < 16; ++nT) {  // Q (scaled), K : [node][dk]
            int h = nT & 7;
            u16* O = (nT < 8) ? qw : kw;
            float sc = (nT < 8) ? 0.25f : 1.0f;
            size_t base = ((size_t)bb * NH + h) * NN + nodebase;
#pragma unroll
            for (int reg = 0; reg < 4; ++reg)
                O[(base + reg) * NDK + col] = f2bf(acc[nT][reg] * sc);
        }
#pragma unroll
        for (int nT = 16; nT < 24; ++nT) {  // V: row-major + transposed
            int h = nT - 16;
            size_t base = ((size_t)bb * NH + h) * NN + nodebase;
#pragma unroll
            for (int reg = 0; reg < 4; ++reg)
                vw[(base + reg) * NDK + col] = f2bf(acc[nT][reg]);
            u32 lo = (u32)f2bf(acc[nT][0]) | ((u32)f2bf(acc[nT][1]) << 16);
            u32 hi = (u32)f2bf(acc[nT][2]) | ((u32)f2bf(acc[nT][3]) << 16);
            *(uint2*)(vt + (((size_t)bb * NH + h) * NDK + col) * NN + nodebase) = make_uint2(lo, hi);
        }
        return;
    }
    // ---- efeat body ----
    {
        int f32 = wave_detect_f32(x16);
        if (tid <= ND) swm[tid] = wmean[tid];
        __syncthreads();
        int sub = tid & 15, grp = tid >> 4;
        size_t eidx = (size_t)(bid - 512) * 16 + grp;
        const float4* wv = (const float4*)&swm[sub * 8];
        float4 w0 = wv[0], w1 = wv[1];
        size_t base = eidx * ND + sub * 8;
        float part;
        if (f32) {
            const float4* p = (const float4*)((const float*)ea + base);
            float4 a0 = p[0], a1 = p[1];
            part = a0.x * w0.x + a0.y * w0.y + a0.z * w0.z + a0.w * w0.w +
                   a1.x * w1.x + a1.y * w1.y + a1.z * w1.z + a1.w * w1.w;
        } else {
            uint4 a = *(const uint4*)((const u16*)ea + base);
            float xv[8];
            unpack8(a, xv);
            part = xv[0] * w0.x + xv[1] * w0.y + xv[2] * w0.z + xv[3] * w0.w +
                   xv[4] * w1.x + xv[5] * w1.y + xv[6] * w1.z + xv[7] * w1.w;
        }
        part += __shfl_xor(part, 1);
        part += __shfl_xor(part, 2);
        part += __shfl_xor(part, 4);
        part += __shfl_xor(part, 8);
        if (sub == 0) {
            size_t b = eidx >> 10;          // NE = 1024 edges/batch
            int pos = posG[eidx];
            featsG[b * NE + pos] = part + swm[ND];
        }
    }
}

// ---------------------------------------------------------------------------
// MFMA flash attention per (h,b), 256 threads. e-domain softmax via __expf
// (fast intrinsic; handles -9e15 -> 0). P packing via pk_bf (compiler-visible
// ops -- safe TRANS consumer). kt loop unrolled 2x (r10): doubles the
// independent QK->softmax->PV chains in flight to attack VALU-idle latency.
// Out scattered to LDS f32 (stride 17, conflict-free); post-pass pulls the
// row into registers, applies sparse edge corrections (dl = e^{s+f}-e^s,
// exact under no-max softmax) with next-edge prefetch.
// LDS = 40,192 B -> 4 blocks/CU. (r9-verified numerics)
// ---------------------------------------------------------------------------
__global__ __launch_bounds__(256, 4) void k_attn(const u16* x16,
                                              const u16* qg, const u16* kg,
                                              const u16* vw, const u16* vt,
                                              const void* mask,
                                              const int* rowstartG, const u16* colsG,
                                              const float* featsG, void* out) {
    __shared__ __align__(16) u16 Ks[NN][24];     // 12,288 B (stride 48B: aligned + bank-spread)
    __shared__ __align__(16) u16 Vs[NDK][264];   //  8,448 B (V^T)
    __shared__ __align__(16) float mb[NN];       //  1,024 B
    __shared__ __align__(16) float Of[NN * 17];  // 17,408 B (out accum, stride 17)
    __shared__ float lbuf[NN];                   //  1,024 B
    int h = blockIdx.x, b = blockIdx.y, tid = threadIdx.x;
    int wv = tid >> 6, lane = tid & 63;
    int col = lane & 15, g = lane >> 4;
    int f32 = wave_detect_f32(x16);
    int mw = wave_detect_mw((const u8*)mask);
    size_t hb = ((size_t)b * NH + h) * NN;
    // issue ALL global loads first (CSR extents, K, V^T, mask, post-pass Q row,
    // Q fragments), then LDS writes: one latency drain instead of several.
    int e0 = rowstartG[b * (NN + 1) + tid];
    int e1 = rowstartG[b * (NN + 1) + tid + 1];
    const uint4* ksrc = (const uint4*)(kg + (hb + tid) * NDK);
    uint4 ka0 = ksrc[0], ka1 = ksrc[1];
    int dk = tid >> 4, chunk = tid & 15;
    const uint4* vsrc = (const uint4*)(vt + ((size_t)(b * NH + h) * NDK + dk) * NN + chunk * 16);
    uint4 va0 = vsrc[0], va1 = vsrc[1];
    bool mv;
    {
        size_t mi = (size_t)b * NN + tid;
        if (mw == 4)      mv = ((const u32*)mask)[mi] != 0;
        else if (mw == 2) mv = ((const u16*)mask)[mi] != 0;
        else              mv = ((const u8*)mask)[mi] != 0;
    }
    // post-pass Q row (kept in regs across the main loop)
    f32x2 qr[8];
    {
        const uint4* qp = (const uint4*)(qg + (hb + tid) * NDK);
        uint4 qa_ = qp[0], qb_ = qp[1];
        qr[0] = bfpair(qa_.x); qr[1] = bfpair(qa_.y);
        qr[2] = bfpair(qa_.z); qr[3] = bfpair(qa_.w);
        qr[4] = bfpair(qb_.x); qr[5] = bfpair(qb_.y);
        qr[6] = bfpair(qb_.z); qr[7] = bfpair(qb_.w);
    }
    // Q B-fragments (k=dk=8g+j zero-padded, n=q=lane&15); Q pre-scaled
    short8 qf[4];
#pragma unroll
    for (int qt = 0; qt < 4; ++qt) {
        int qtabs = wv * 4 + qt;
        short8 qv = {0, 0, 0, 0, 0, 0, 0, 0};
        if (g < 2)
            qv = *(const short8*)(qg + (hb + qtabs * 16 + col) * NDK + 8 * g);
        qf[qt] = qv;
    }
    {   // LDS writes
        uint4* kdst = (uint4*)&Ks[tid][0];
        kdst[0] = ka0; kdst[1] = ka1;
        uint4* vdst = (uint4*)&Vs[dk][chunk * 16];
        vdst[0] = va0; vdst[1] = va1;
        mb[tid] = mv ? 0.0f : NEGV;
    }
    __syncthreads();

    float4v outv[4];
    float lpart[4];
#pragma unroll
    for (int qt = 0; qt < 4; ++qt) {
        outv[qt] = (float4v){0.f, 0.f, 0.f, 0.f};
        lpart[qt] = 0.f;
    }

#pragma unroll 2
    for (int kt = 0; kt < 16; ++kt) {
        short8 kf = {0, 0, 0, 0, 0, 0, 0, 0};
        if (g < 2) kf = *(const short8*)&Ks[kt * 16 + col][8 * g];
        Pack8 vv;
        {
            uint2 t2 = *(const uint2*)&Vs[col][kt * 16 + 4 * g];
            vv.w[0] = t2.x; vv.w[1] = t2.y; vv.w[2] = 0; vv.w[3] = 0;
        }
        float4 mb4 = *(const float4*)&mb[kt * 16 + 4 * g];
        float4v cin = (float4v){mb4.x, mb4.y, mb4.z, mb4.w};
#pragma unroll
        for (int qt = 0; qt < 4; ++qt) {
            float4v s4 = __builtin_amdgcn_mfma_f32_16x16x32_bf16(kf, qf[qt], cin, 0, 0, 0);
            float p0 = __expf(fminf(s4[0], 60.f));
            float p1 = __expf(fminf(s4[1], 60.f));
            float p2 = __expf(fminf(s4[2], 60.f));
            float p3 = __expf(fminf(s4[3], 60.f));
            lpart[qt] += (p0 + p1) + (p2 + p3);
            Pack8 pp;
            pp.w[0] = pk_bf(p0, p1);
            pp.w[1] = pk_bf(p2, p3);
            pp.w[2] = 0; pp.w[3] = 0;
            outv[qt] = __builtin_amdgcn_mfma_f32_16x16x32_bf16(pp.v, vv.v, outv[qt], 0, 0, 0);
        }
    }
    // l reduce across g groups; scatter out to LDS (stride-17 rows)
#pragma unroll
    for (int qt = 0; qt < 4; ++qt) {
        float l = lpart[qt];
        l += __shfl_xor(l, 16);
        l += __shfl_xor(l, 32);
        if (g == 0) lbuf[(wv * 4 + qt) * 16 + col] = l;
        int q0 = (wv * 4 + qt) * 16 + 4 * g;
#pragma unroll
        for (int reg = 0; reg < 4; ++reg)
            Of[(q0 + reg) * 17 + col] = outv[qt][reg];
    }
    __syncthreads();

    // per-query edge corrections: thread tid owns q=tid (exclusive row), all
    // accumulation in registers; next-edge prefetch hides dependent loads.
    float lfin = lbuf[tid];
    f32x2 r[8];
#pragma unroll
    for (int j = 0; j < 8; ++j)
        r[j] = (f32x2){Of[tid * 17 + 2 * j], Of[tid * 17 + 2 * j + 1]};
    if (e0 < e1) {
        const u16* colsB = colsG + (size_t)b * NE;
        const float* featsB = featsG + (size_t)b * NE;
        int c = colsB[e0];
        float f = featsB[e0];
        const uint4* vp0 = (const uint4*)(vw + (hb + c) * NDK);
        uint4 v0 = vp0[0], v1 = vp0[1];
        for (int e = e0; e < e1; ++e) {
            int cc_ = c; float ff_ = f;
            uint4 w0 = v0, w1 = v1;
            if (e + 1 < e1) {  // prefetch next edge
                c = colsB[e + 1];
                f = featsB[e + 1];
                const uint4* vp = (const uint4*)(vw + (hb + c) * NDK);
                v0 = vp[0]; v1 = vp[1];
            }
            const u32* kcw = (const u32*)&Ks[cc_][0];   // cc_*48B: 16-aligned
            f32x2 s2 = qr[0] * bfpair(kcw[0]);
            s2 += qr[1] * bfpair(kcw[1]); s2 += qr[2] * bfpair(kcw[2]);
            s2 += qr[3] * bfpair(kcw[3]); s2 += qr[4] * bfpair(kcw[4]);
            s2 += qr[5] * bfpair(kcw[5]); s2 += qr[6] * bfpair(kcw[6]);
            s2 += qr[7] * bfpair(kcw[7]);
            float s = s2.x + s2.y + mb[cc_];
            float dl = __expf(fminf(s + ff_, 60.f)) - __expf(fminf(s, 60.f));
            lfin += dl;
            f32x2 d2 = (f32x2){dl, dl};
            r[0] += d2 * bfpair(w0.x); r[1] += d2 * bfpair(w0.y);
            r[2] += d2 * bfpair(w0.z); r[3] += d2 * bfpair(w0.w);
            r[4] += d2 * bfpair(w1.x); r[5] += d2 * bfpair(w1.y);
            r[6] += d2 * bfpair(w1.z); r[7] += d2 * bfpair(w1.w);
        }
    }
    // final: own row, from registers, vectorized global write
    float inv = 1.0f / lfin;  // mask[:,0]=True -> l > 0
    size_t obase = ((size_t)(b * NN + tid)) * ND + h * NDK;
    if (f32) {
        float4* op = (float4*)((float*)out + obase);  // 64B-aligned (obase % 16 == 0)
#pragma unroll
        for (int jj = 0; jj < 4; ++jj) {
            float4 w;
            w.x = r[2 * jj].x * inv;     w.y = r[2 * jj].y * inv;
            w.z = r[2 * jj + 1].x * inv; w.w = r[2 * jj + 1].y * inv;
            op[jj] = w;
        }
    } else {
        u16* op = (u16*)out + obase;  // 32B-aligned
        Pack8 pa, pb;
#pragma unroll
        for (int jj = 0; jj < 4; ++jj) {
            pa.u[2 * jj]     = f2bf(r[jj].x * inv);
            pa.u[2 * jj + 1] = f2bf(r[jj].y * inv);
            pb.u[2 * jj]     = f2bf(r[jj + 4].x * inv);
            pb.u[2 * jj + 1] = f2bf(r[jj + 4].y * inv);
        }
        *(uint4*)op = *(uint4*)&pa.w[0];
        *(uint4*)(op + 8) = *(uint4*)&pb.w[0];
    }
}

// ---------------------------------------------------------------------------
// In-place residual + LayerNorm on d_out. One wave per row. (verified)
// ---------------------------------------------------------------------------
__global__ __launch_bounds__(256) void k_ln(void* out, const void* x, const void* g,
                                            const void* be) {
    int f32 = wave_detect_f32((const u16*)x);
    int tid = threadIdx.x, wv = tid >> 6, lane = tid & 63;
    int row = blockIdx.x * 4 + wv;
    size_t base = (size_t)row * ND;
    float v0 = ldf(out, base + lane, f32) + ldf(x, base + lane, f32);
    float v1 = ldf(out, base + lane + 64, f32) + ldf(x, base + lane + 64, f32);
    float s = v0 + v1, ss = v0 * v0 + v1 * v1;
#pragma unroll
    for (int off = 32; off; off >>= 1) {
        s += __shfl_xor(s, off, 64);
        ss += __shfl_xor(ss, off, 64);
    }
    float mu = s * (1.0f / ND);
    float var = ss * (1.0f / ND) - mu * mu;
    float rs = rsqrtf(var + 1e-6f);
    float o0 = (v0 - mu) * rs * ldf(g, lane, f32) + ldf(be, lane, f32);
    float o1 = (v1 - mu) * rs * ldf(g, lane + 64, f32) + ldf(be, lane + 64, f32);
    stf(out, base + lane, f32, o0);
    stf(out, base + lane + 64, f32, o1);
}

// ---------------------------------------------------------------------------
extern "C" void kernel_launch(void* const* d_in, const int* in_sizes, int n_in,
                              void* d_out, int out_size, void* d_ws, size_t ws_size,
                              hipStream_t stream) {
    const void* x = d_in[0];
    const void* mask = d_in[1];
    const int* ei = (const int*)d_in[2];
    const void* ea = d_in[3];
    const void* Wq = d_in[4];
    const void* Wk = d_in[5];
    const void* Wv = d_in[6];
    const void* Wew = d_in[7];
    const void* Web = d_in[8];
    const void* lng = d_in[9];
    const void* lnb = d_in[10];

    char* ws = (char*)d_ws;
    size_t off = 0;
    float* wmean = (float*)(ws + off);   off += 1024;
    float* degr = (float*)(ws + off);    off += (size_t)NB * NN * 4;
    float* degc = (float*)(ws + off);    off += (size_t)NB * NN * 4;
    int* rowstart = (int*)(ws + off);    off += (size_t)NB * (NN + 1) * 4 + 512;
    u16* colsG = (u16*)(ws + off);       off += (size_t)NB * NE * 2;
    u16* posG = (u16*)(ws + off);        off += (size_t)NB * NE * 2;
    float* featsG = (float*)(ws + off);  off += (size_t)NB * NE * 4;
    u16* WP = (u16*)(ws + off);          off += (size_t)5 * 24 * 64 * 8 * 2;
    const size_t qkv_elems = (size_t)NB * NH * NN * NDK;
    u16* qw = (u16*)(ws + off);          off += qkv_elems * 2;
    u16* kw = (u16*)(ws + off);          off += qkv_elems * 2;
    u16* vw = (u16*)(ws + off);          off += qkv_elems * 2;  // row-major V
    u16* vt = (u16*)(ws + off);          off += qkv_elems * 2;  // transposed V

    k_pre<<<377, 256, 0, stream>>>((const u16*)x, Wew, Web, wmean, Wq, Wk, Wv, WP,
                                   ei, degr, degc, rowstart, colsG, posG);
    k_mid<<<512 + (NB * NE) / 16, 256, 0, stream>>>((const u16*)x, x, degr, degc, WP,
                                                    qw, kw, vw, vt, ea, wmean, posG,
                                                    featsG);
    k_attn<<<dim3(NH, NB), 256, 0, stream>>>((const u16*)x, qw, kw, vw, vt, mask,
                                             rowstart, colsG, featsG, d_out);
    k_ln<<<(NB * NN) / 4, 256, 0, stream>>>(d_out, x, lng, lnb);
}

// Round 11
// 201.066 us; speedup vs baseline: 1.0795x; 1.0795x over previous
//
#include <hip/hip_runtime.h>
#include <stdint.h>

// Graphormer layer constants
#define NB 128   // batch
#define NN 256   // nodes
#define NE 1024  // edges
#define ND 128   // model dim
#define NH 8     // heads
#define NDK 16   // head dim
#define NEGV -9.0e15f

typedef unsigned short u16;
typedef unsigned int u32;
typedef unsigned char u8;
typedef __attribute__((ext_vector_type(8))) short short8;
typedef __attribute__((ext_vector_type(4))) float float4v;
typedef __attribute__((ext_vector_type(2))) float f32x2;

__device__ __forceinline__ float bf2f(u16 u) { return __uint_as_float(((u32)u) << 16); }
__device__ __forceinline__ u16 f2bf(float f) {
    u32 u = __float_as_uint(f);
    u += 0x7fffu + ((u >> 16) & 1u);  // round-to-nearest-even
    return (u16)(u >> 16);
}
__device__ __forceinline__ float ldf(const void* p, size_t i, int f32) {
    return f32 ? ((const float*)p)[i] : bf2f(((const u16*)p)[i]);
}
__device__ __forceinline__ void stf(void* p, size_t i, int f32, float v) {
    if (f32) ((float*)p)[i] = v;
    else ((u16*)p)[i] = f2bf(v);
}
__device__ __forceinline__ void unpack8(uint4 a, float* o) {
    o[0] = bf2f(a.x & 0xffff); o[1] = bf2f(a.x >> 16);
    o[2] = bf2f(a.y & 0xffff); o[3] = bf2f(a.y >> 16);
    o[4] = bf2f(a.z & 0xffff); o[5] = bf2f(a.z >> 16);
    o[6] = bf2f(a.w & 0xffff); o[7] = bf2f(a.w >> 16);
}
// {low bf16, high bf16} of a u32 word -> f32x2
__device__ __forceinline__ f32x2 bfpair(u32 w) {
    return (f32x2){__uint_as_float(w << 16), __uint_as_float(w & 0xffff0000u)};
}
// pack two f32 -> two bf16 (round-nearest-up; p>=0 finite). Compiler-visible
// ops only: safe consumer of TRANS (v_exp) results. (Inline-asm cvt_pk here
// hit the TRANS->inline-asm hazard -> NaN, r2-r5 post-mortem.)
__device__ __forceinline__ u32 pk_bf(float a, float b) {
    return ((__float_as_uint(a) + 0x8000u) >> 16) |
           ((__float_as_uint(b) + 0x8000u) & 0xffff0000u);
}
union Pack8 { u16 u[8]; u32 w[4]; short8 v; };

// ---------------------------------------------------------------------------
// Per-wave format self-detect (replaces the k_detect kernel + flags buffer).
// Every wave reads the SAME first 1KB of x / mask -> deterministic, identical
// result in all waves/blocks. f32 probe covers 256 low-halfwords (false-neg
// P = 0.76^256 ~ 1e-31); mask probe covers 1024 bytes. (r8/r9-verified PASS)
// ---------------------------------------------------------------------------
__device__ __forceinline__ int wave_detect_f32(const u16* x16) {
    int lane = threadIdx.x & 63;
    uint4 a = *(const uint4*)(x16 + lane * 8);
    u32 w[4] = {a.x, a.y, a.z, a.w};
    u32 ev = 0;
#pragma unroll
    for (int j = 0; j < 4; ++j) {
        ev |= ((((w[j] & 0xffffu) >> 7) & 0xffu) >= 0xC2u) ? 1u : 0u;
        ev |= (((w[j] >> 23) & 0xffu) >= 0xC2u) ? 1u : 0u;
    }
#pragma unroll
    for (int off = 32; off; off >>= 1) ev |= (u32)__shfl_xor((int)ev, off, 64);
    return ev ? 1 : 0;
}
__device__ __forceinline__ int wave_detect_mw(const u8* m8) {
    int lane = threadIdx.x & 63;
    uint4 m = *(const uint4*)(m8 + lane * 16);
    u32 w[4] = {m.x, m.y, m.z, m.w};
    u32 g1 = 0, mx = 0;
#pragma unroll
    for (int j = 0; j < 4; ++j) {
        u32 b0 = w[j] & 0xffu, b1 = (w[j] >> 8) & 0xffu;
        u32 b2 = (w[j] >> 16) & 0xffu, b3 = w[j] >> 24;
        g1 |= b1;  // (idx&3)==1 bytes
        u32 ma = b0 > b1 ? b0 : b1, mb2 = b2 > b3 ? b2 : b3;
        u32 mc = ma > mb2 ? ma : mb2;
        mx = mx > mc ? mx : mc;
    }
#pragma unroll
    for (int off = 32; off; off >>= 1) {
        g1 |= (u32)__shfl_xor((int)g1, off, 64);
        u32 o = (u32)__shfl_xor((int)mx, off, 64);
        mx = mx > o ? mx : o;
    }
    return (g1 == 0) ? 4 : ((mx <= 1u) ? 1 : 2);
}

// ---------------------------------------------------------------------------
// Fused preprocessing (r9-verified): blocks 0..248 do wmean (129) + packB
// (120) on 64 active lanes; blocks 249..376 do per-batch CSR writing the
// sort permutation posG[e]=pos (decoupled from edge features).
// ---------------------------------------------------------------------------
__global__ __launch_bounds__(256) void k_pre(const u16* x16,
                                             const void* Wew, const void* Web,
                                             float* wmean,
                                             const void* Wq, const void* Wk,
                                             const void* Wv, u16* WP,
                                             const int* ei, float* degr, float* degc,
                                             int* rowstartG, u16* colsG, u16* posG) {
    int bid = blockIdx.x, tid = threadIdx.x;
    if (bid < 249) {
        if (tid < 64) {
            int f32 = wave_detect_f32(x16);
            int lane = tid;
            if (bid < 129) {
                int k = bid;
                const void* src = (k < 128) ? Wew : Web;
                size_t base = (k < 128) ? (size_t)k * ND : 0;
                float s = ldf(src, base + lane, f32) + ldf(src, base + lane + 64, f32);
#pragma unroll
                for (int off = 32; off; off >>= 1) s += __shfl_xor(s, off, 64);
                if (lane == 0) wmean[k] = s * (1.0f / ND);
            } else {
                int id = bid - 129;
                int kT = id / 24, nT = id % 24;
                int col = lane & 15, quad = lane >> 4;
                int n = nT * 16 + col;
                int mat = n >> 7, nm = n & 127;
                const void* W = (mat == 0) ? Wq : (mat == 1) ? Wk : Wv;
                Pack8 c;
#pragma unroll
                for (int j = 0; j < 8; ++j) {
                    int k = kT * 32 + quad * 8 + j;
                    c.u[j] = (k < 130) ? f2bf(ldf(W, (size_t)k * ND + nm, f32)) : (u16)0;
                }
                *(short8*)(WP + ((size_t)(kT * 24 + nT) * 64 + lane) * 8) = c.v;
            }
        }
        return;
    }
    // ---- CSR for batch b (verbatim r6 body; feats scatter -> posG perm) ----
    __shared__ int cr[NN], cc[NN], offs[NN], rs[NN + 1];
    int b = bid - 249;
    cr[tid] = 0; cc[tid] = 0;
    __syncthreads();
    const int* rows = ei + (size_t)b * 2 * NE;   // (B,2,E)
    const int* cols = rows + NE;
    for (int e = tid; e < NE; e += 256) {
        atomicAdd(&cr[rows[e]], 1);
        atomicAdd(&cc[cols[e]], 1);
    }
    __syncthreads();
    degr[b * NN + tid] = (float)cr[tid];
    degc[b * NN + tid] = (float)cc[tid];
    if (tid == 0) {
        int a = 0;
        for (int n = 0; n < NN; ++n) { rs[n] = a; a += cr[n]; }
        rs[NN] = a;
    }
    __syncthreads();
    offs[tid] = rs[tid];
    rowstartG[b * (NN + 1) + tid] = rs[tid];
    if (tid == 0) rowstartG[b * (NN + 1) + NN] = rs[NN];
    __syncthreads();
    for (int e = tid; e < NE; e += 256) {
        int r = rows[e];
        int pos = atomicAdd(&offs[r], 1);
        colsG[(size_t)b * NE + pos] = (u16)cols[e];
        posG[(size_t)b * NE + e] = (u16)pos;
    }
}

// ---------------------------------------------------------------------------
// Edge features, saturating grid (r9-verified, SEPARATE kernel again --
// r10 lesson: fusing with the 104-VGPR gemm body inherited worst-case
// regalloc and collapsed this kernel's occupancy/BW 16%->done at 60us).
// 16 lanes/edge, 16 edges/block, 8192 blocks, one 16B load/thread.
// Writes directly to the row-sorted slot via posG.
// ---------------------------------------------------------------------------
__global__ __launch_bounds__(256) void k_efeat(const u16* x16, const void* ea,
                                               const float* wmean, const u16* posG,
                                               float* featsG) {
    __shared__ __align__(16) float swm[132];
    int tid = threadIdx.x;
    int f32 = wave_detect_f32(x16);
    if (tid <= ND) swm[tid] = wmean[tid];
    __syncthreads();
    int sub = tid & 15, grp = tid >> 4;
    size_t eidx = (size_t)blockIdx.x * 16 + grp;
    const float4* wv = (const float4*)&swm[sub * 8];
    float4 w0 = wv[0], w1 = wv[1];
    size_t base = eidx * ND + sub * 8;
    float part;
    if (f32) {
        const float4* p = (const float4*)((const float*)ea + base);
        float4 a0 = p[0], a1 = p[1];
        part = a0.x * w0.x + a0.y * w0.y + a0.z * w0.z + a0.w * w0.w +
               a1.x * w1.x + a1.y * w1.y + a1.z * w1.z + a1.w * w1.w;
    } else {
        uint4 a = *(const uint4*)((const u16*)ea + base);
        float xv[8];
        unpack8(a, xv);
        part = xv[0] * w0.x + xv[1] * w0.y + xv[2] * w0.z + xv[3] * w0.w +
               xv[4] * w1.x + xv[5] * w1.y + xv[6] * w1.z + xv[7] * w1.w;
    }
    part += __shfl_xor(part, 1);
    part += __shfl_xor(part, 2);
    part += __shfl_xor(part, 4);
    part += __shfl_xor(part, 8);
    if (sub == 0) {
        size_t b = eidx >> 10;          // NE = 1024 edges/batch
        int pos = posG[eidx];
        featsG[b * NE + pos] = part + swm[ND];
    }
}

// ---------------------------------------------------------------------------
// MFMA QKV GEMM (r9-verified, separate kernel). Q (pre-scaled by 0.25),
// K -> [b][h][node][dk]; V -> row-major vw AND transposed vt.
// ---------------------------------------------------------------------------
__global__ __launch_bounds__(256) void k_gemm(const void* x, const float* degr,
                                              const float* degc, const u16* WP,
                                              u16* qw, u16* kw,
                                              u16* vw, u16* vt) {
    int tid = threadIdx.x;
    int w = tid >> 6, lane = tid & 63;
    int quad = lane >> 4, col = lane & 15;
    int m0 = blockIdx.x * 64 + w * 16;
    int row = m0 + col;
    int f32 = wave_detect_f32((const u16*)x);

    float4v acc[24];
#pragma unroll
    for (int t = 0; t < 24; ++t) acc[t] = (float4v){0.f, 0.f, 0.f, 0.f};

    const short8* wp = (const short8*)WP;
    for (int kT = 0; kT < 5; ++kT) {
        short8 a;
        if (kT < 4) {
            if (!f32) {
                a = *(const short8*)((const u16*)x + (size_t)row * ND + kT * 32 + quad * 8);
            } else {
                const float* xf = (const float*)x + (size_t)row * ND + kT * 32 + quad * 8;
                Pack8 c;
#pragma unroll
                for (int j = 0; j < 8; ++j) c.u[j] = f2bf(xf[j]);
                a = c.v;
            }
        } else {
            Pack8 c;
#pragma unroll
            for (int j = 0; j < 8; ++j) c.u[j] = 0;
            if (quad == 0) {
                c.u[0] = f2bf(degr[row]);
                c.u[1] = f2bf(degc[row]);
            }
            a = c.v;
        }
#pragma unroll
        for (int nT = 0; nT < 24; ++nT) {
            short8 bfr = wp[(size_t)(kT * 24 + nT) * 64 + lane];
            acc[nT] = __builtin_amdgcn_mfma_f32_16x16x32_bf16(a, bfr, acc[nT], 0, 0, 0);
        }
    }
    int bb = m0 >> 8;
    int nodebase = (m0 & 255) + quad * 4;
#pragma unroll
    for (int nT = 0; nT < 16; ++nT) {  // Q (scaled), K : [node][dk]
        int h = nT & 7;
        u16* O = (nT < 8) ? qw : kw;
        float sc = (nT < 8) ? 0.25f : 1.0f;
        size_t base = ((size_t)bb * NH + h) * NN + nodebase;
#pragma unroll
        for (int reg = 0; reg < 4; ++reg)
            O[(base + reg) * NDK + col] = f2bf(acc[nT][reg] * sc);
    }
#pragma unroll
    for (int nT = 16; nT < 24; ++nT) {  // V: row-major + transposed
        int h = nT - 16;
        size_t base = ((size_t)bb * NH + h) * NN + nodebase;
#pragma unroll
        for (int reg = 0; reg < 4; ++reg)
            vw[(base + reg) * NDK + col] = f2bf(acc[nT][reg]);
        u32 lo = (u32)f2bf(acc[nT][0]) | ((u32)f2bf(acc[nT][1]) << 16);
        u32 hi = (u32)f2bf(acc[nT][2]) | ((u32)f2bf(acc[nT][3]) << 16);
        *(uint2*)(vt + (((size_t)bb * NH + h) * NDK + col) * NN + nodebase) = make_uint2(lo, hi);
    }
}

// ---------------------------------------------------------------------------
// MFMA flash attention per (h,b), 256 threads. e-domain softmax via __expf
// (fast intrinsic; handles -9e15 -> 0). P packing via pk_bf (compiler-visible
// ops -- safe TRANS consumer). kt loop unrolled 2x (r10-verified correctness;
// doubles the independent QK->exp->PV chains in flight; r10's total suggests
// ~20us gain, isolated this round). Out scattered to LDS f32 (stride 17,
// conflict-free); post-pass in registers with next-edge prefetch.
// LDS = 40,192 B -> 4 blocks/CU.
// ---------------------------------------------------------------------------
__global__ __launch_bounds__(256, 4) void k_attn(const u16* x16,
                                              const u16* qg, const u16* kg,
                                              const u16* vw, const u16* vt,
                                              const void* mask,
                                              const int* rowstartG, const u16* colsG,
                                              const float* featsG, void* out) {
    __shared__ __align__(16) u16 Ks[NN][24];     // 12,288 B (stride 48B: aligned + bank-spread)
    __shared__ __align__(16) u16 Vs[NDK][264];   //  8,448 B (V^T)
    __shared__ __align__(16) float mb[NN];       //  1,024 B
    __shared__ __align__(16) float Of[NN * 17];  // 17,408 B (out accum, stride 17)
    __shared__ float lbuf[NN];                   //  1,024 B
    int h = blockIdx.x, b = blockIdx.y, tid = threadIdx.x;
    int wv = tid >> 6, lane = tid & 63;
    int col = lane & 15, g = lane >> 4;
    int f32 = wave_detect_f32(x16);
    int mw = wave_detect_mw((const u8*)mask);
    size_t hb = ((size_t)b * NH + h) * NN;
    // issue ALL global loads first (CSR extents, K, V^T, mask, post-pass Q row,
    // Q fragments), then LDS writes: one latency drain instead of several.
    int e0 = rowstartG[b * (NN + 1) + tid];
    int e1 = rowstartG[b * (NN + 1) + tid + 1];
    const uint4* ksrc = (const uint4*)(kg + (hb + tid) * NDK);
    uint4 ka0 = ksrc[0], ka1 = ksrc[1];
    int dk = tid >> 4, chunk = tid & 15;
    const uint4* vsrc = (const uint4*)(vt + ((size_t)(b * NH + h) * NDK + dk) * NN + chunk * 16);
    uint4 va0 = vsrc[0], va1 = vsrc[1];
    bool mv;
    {
        size_t mi = (size_t)b * NN + tid;
        if (mw == 4)      mv = ((const u32*)mask)[mi] != 0;
        else if (mw == 2) mv = ((const u16*)mask)[mi] != 0;
        else              mv = ((const u8*)mask)[mi] != 0;
    }
    // post-pass Q row (kept in regs across the main loop)
    f32x2 qr[8];
    {
        const uint4* qp = (const uint4*)(qg + (hb + tid) * NDK);
        uint4 qa_ = qp[0], qb_ = qp[1];
        qr[0] = bfpair(qa_.x); qr[1] = bfpair(qa_.y);
        qr[2] = bfpair(qa_.z); qr[3] = bfpair(qa_.w);
        qr[4] = bfpair(qb_.x); qr[5] = bfpair(qb_.y);
        qr[6] = bfpair(qb_.z); qr[7] = bfpair(qb_.w);
    }
    // Q B-fragments (k=dk=8g+j zero-padded, n=q=lane&15); Q pre-scaled
    short8 qf[4];
#pragma unroll
    for (int qt = 0; qt < 4; ++qt) {
        int qtabs = wv * 4 + qt;
        short8 qv = {0, 0, 0, 0, 0, 0, 0, 0};
        if (g < 2)
            qv = *(const short8*)(qg + (hb + qtabs * 16 + col) * NDK + 8 * g);
        qf[qt] = qv;
    }
    {   // LDS writes
        uint4* kdst = (uint4*)&Ks[tid][0];
        kdst[0] = ka0; kdst[1] = ka1;
        uint4* vdst = (uint4*)&Vs[dk][chunk * 16];
        vdst[0] = va0; vdst[1] = va1;
        mb[tid] = mv ? 0.0f : NEGV;
    }
    __syncthreads();

    float4v outv[4];
    float lpart[4];
#pragma unroll
    for (int qt = 0; qt < 4; ++qt) {
        outv[qt] = (float4v){0.f, 0.f, 0.f, 0.f};
        lpart[qt] = 0.f;
    }

#pragma unroll 2
    for (int kt = 0; kt < 16; ++kt) {
        short8 kf = {0, 0, 0, 0, 0, 0, 0, 0};
        if (g < 2) kf = *(const short8*)&Ks[kt * 16 + col][8 * g];
        Pack8 vv;
        {
            uint2 t2 = *(const uint2*)&Vs[col][kt * 16 + 4 * g];
            vv.w[0] = t2.x; vv.w[1] = t2.y; vv.w[2] = 0; vv.w[3] = 0;
        }
        float4 mb4 = *(const float4*)&mb[kt * 16 + 4 * g];
        float4v cin = (float4v){mb4.x, mb4.y, mb4.z, mb4.w};
#pragma unroll
        for (int qt = 0; qt < 4; ++qt) {
            float4v s4 = __builtin_amdgcn_mfma_f32_16x16x32_bf16(kf, qf[qt], cin, 0, 0, 0);
            float p0 = __expf(fminf(s4[0], 60.f));
            float p1 = __expf(fminf(s4[1], 60.f));
            float p2 = __expf(fminf(s4[2], 60.f));
            float p3 = __expf(fminf(s4[3], 60.f));
            lpart[qt] += (p0 + p1) + (p2 + p3);
            Pack8 pp;
            pp.w[0] = pk_bf(p0, p1);
            pp.w[1] = pk_bf(p2, p3);
            pp.w[2] = 0; pp.w[3] = 0;
            outv[qt] = __builtin_amdgcn_mfma_f32_16x16x32_bf16(pp.v, vv.v, outv[qt], 0, 0, 0);
        }
    }
    // l reduce across g groups; scatter out to LDS (stride-17 rows)
#pragma unroll
    for (int qt = 0; qt < 4; ++qt) {
        float l = lpart[qt];
        l += __shfl_xor(l, 16);
        l += __shfl_xor(l, 32);
        if (g == 0) lbuf[(wv * 4 + qt) * 16 + col] = l;
        int q0 = (wv * 4 + qt) * 16 + 4 * g;
#pragma unroll
        for (int reg = 0; reg < 4; ++reg)
            Of[(q0 + reg) * 17 + col] = outv[qt][reg];
    }
    __syncthreads();

    // per-query edge corrections: thread tid owns q=tid (exclusive row), all
    // accumulation in registers; next-edge prefetch hides dependent loads.
    float lfin = lbuf[tid];
    f32x2 r[8];
#pragma unroll
    for (int j = 0; j < 8; ++j)
        r[j] = (f32x2){Of[tid * 17 + 2 * j], Of[tid * 17 + 2 * j + 1]};
    if (e0 < e1) {
        const u16* colsB = colsG + (size_t)b * NE;
        const float* featsB = featsG + (size_t)b * NE;
        int c = colsB[e0];
        float f = featsB[e0];
        const uint4* vp0 = (const uint4*)(vw + (hb + c) * NDK);
        uint4 v0 = vp0[0], v1 = vp0[1];
        for (int e = e0; e < e1; ++e) {
            int cc_ = c; float ff_ = f;
            uint4 w0 = v0, w1 = v1;
            if (e + 1 < e1) {  // prefetch next edge
                c = colsB[e + 1];
                f = featsB[e + 1];
                const uint4* vp = (const uint4*)(vw + (hb + c) * NDK);
                v0 = vp[0]; v1 = vp[1];
            }
            const u32* kcw = (const u32*)&Ks[cc_][0];   // cc_*48B: 16-aligned
            f32x2 s2 = qr[0] * bfpair(kcw[0]);
            s2 += qr[1] * bfpair(kcw[1]); s2 += qr[2] * bfpair(kcw[2]);
            s2 += qr[3] * bfpair(kcw[3]); s2 += qr[4] * bfpair(kcw[4]);
            s2 += qr[5] * bfpair(kcw[5]); s2 += qr[6] * bfpair(kcw[6]);
            s2 += qr[7] * bfpair(kcw[7]);
            float s = s2.x + s2.y + mb[cc_];
            float dl = __expf(fminf(s + ff_, 60.f)) - __expf(fminf(s, 60.f));
            lfin += dl;
            f32x2 d2 = (f32x2){dl, dl};
            r[0] += d2 * bfpair(w0.x); r[1] += d2 * bfpair(w0.y);
            r[2] += d2 * bfpair(w0.z); r[3] += d2 * bfpair(w0.w);
            r[4] += d2 * bfpair(w1.x); r[5] += d2 * bfpair(w1.y);
            r[6] += d2 * bfpair(w1.z); r[7] += d2 * bfpair(w1.w);
        }
    }
    // final: own row, from registers, vectorized global write
    float inv = 1.0f / lfin;  // mask[:,0]=True -> l > 0
    size_t obase = ((size_t)(b * NN + tid)) * ND + h * NDK;
    if (f32) {
        float4* op = (float4*)((float*)out + obase);  // 64B-aligned (obase % 16 == 0)
#pragma unroll
        for (int jj = 0; jj < 4; ++jj) {
            float4 w;
            w.x = r[2 * jj].x * inv;     w.y = r[2 * jj].y * inv;
            w.z = r[2 * jj + 1].x * inv; w.w = r[2 * jj + 1].y * inv;
            op[jj] = w;
        }
    } else {
        u16* op = (u16*)out + obase;  // 32B-aligned
        Pack8 pa, pb;
#pragma unroll
        for (int jj = 0; jj < 4; ++jj) {
            pa.u[2 * jj]     = f2bf(r[jj].x * inv);
            pa.u[2 * jj + 1] = f2bf(r[jj].y * inv);
            pb.u[2 * jj]     = f2bf(r[jj + 4].x * inv);
            pb.u[2 * jj + 1] = f2bf(r[jj + 4].y * inv);
        }
        *(uint4*)op = *(uint4*)&pa.w[0];
        *(uint4*)(op + 8) = *(uint4*)&pb.w[0];
    }
}

// ---------------------------------------------------------------------------
// In-place residual + LayerNorm on d_out. One wave per row. (verified)
// ---------------------------------------------------------------------------
__global__ __launch_bounds__(256) void k_ln(void* out, const void* x, const void* g,
                                            const void* be) {
    int f32 = wave_detect_f32((const u16*)x);
    int tid = threadIdx.x, wv = tid >> 6, lane = tid & 63;
    int row = blockIdx.x * 4 + wv;
    size_t base = (size_t)row * ND;
    float v0 = ldf(out, base + lane, f32) + ldf(x, base + lane, f32);
    float v1 = ldf(out, base + lane + 64, f32) + ldf(x, base + lane + 64, f32);
    float s = v0 + v1, ss = v0 * v0 + v1 * v1;
#pragma unroll
    for (int off = 32; off; off >>= 1) {
        s += __shfl_xor(s, off, 64);
        ss += __shfl_xor(ss, off, 64);
    }
    float mu = s * (1.0f / ND);
    float var = ss * (1.0f / ND) - mu * mu;
    float rs = rsqrtf(var + 1e-6f);
    float o0 = (v0 - mu) * rs * ldf(g, lane, f32) + ldf(be, lane, f32);
    float o1 = (v1 - mu) * rs * ldf(g, lane + 64, f32) + ldf(be, lane + 64, f32);
    stf(out, base + lane, f32, o0);
    stf(out, base + lane + 64, f32, o1);
}

// ---------------------------------------------------------------------------
extern "C" void kernel_launch(void* const* d_in, const int* in_sizes, int n_in,
                              void* d_out, int out_size, void* d_ws, size_t ws_size,
                              hipStream_t stream) {
    const void* x = d_in[0];
    const void* mask = d_in[1];
    const int* ei = (const int*)d_in[2];
    const void* ea = d_in[3];
    const void* Wq = d_in[4];
    const void* Wk = d_in[5];
    const void* Wv = d_in[6];
    const void* Wew = d_in[7];
    const void* Web = d_in[8];
    const void* lng = d_in[9];
    const void* lnb = d_in[10];

    char* ws = (char*)d_ws;
    size_t off = 0;
    float* wmean = (float*)(ws + off);   off += 1024;
    float* degr = (float*)(ws + off);    off += (size_t)NB * NN * 4;
    float* degc = (float*)(ws + off);    off += (size_t)NB * NN * 4;
    int* rowstart = (int*)(ws + off);    off += (size_t)NB * (NN + 1) * 4 + 512;
    u16* colsG = (u16*)(ws + off);       off += (size_t)NB * NE * 2;
    u16* posG = (u16*)(ws + off);        off += (size_t)NB * NE * 2;
    float* featsG = (float*)(ws + off);  off += (size_t)NB * NE * 4;
    u16* WP = (u16*)(ws + off);          off += (size_t)5 * 24 * 64 * 8 * 2;
    const size_t qkv_elems = (size_t)NB * NH * NN * NDK;
    u16* qw = (u16*)(ws + off);          off += qkv_elems * 2;
    u16* kw = (u16*)(ws + off);          off += qkv_elems * 2;
    u16* vw = (u16*)(ws + off);          off += qkv_elems * 2;  // row-major V
    u16* vt = (u16*)(ws + off);          off += qkv_elems * 2;  // transposed V

    k_pre<<<377, 256, 0, stream>>>((const u16*)x, Wew, Web, wmean, Wq, Wk, Wv, WP,
                                   ei, degr, degc, rowstart, colsG, posG);
    k_efeat<<<(NB * NE) / 16, 256, 0, stream>>>((const u16*)x, ea, wmean, posG, featsG);
    k_gemm<<<(NB * NN) / 64, 256, 0, stream>>>(x, degr, degc, WP, qw, kw, vw, vt);
    k_attn<<<dim3(NH, NB), 256, 0, stream>>>((const u16*)x, qw, kw, vw, vt, mask,
                                             rowstart, colsG, featsG, d_out);
    k_ln<<<(NB * NN) / 4, 256, 0, stream>>>(d_out, x, lng, lnb);
}